// Round 2
// baseline (2971.823 us; speedup 1.0000x reference)
//
#include <hip/hip_runtime.h>
#include <math.h>

// ---------------------------------------------------------------------------
// conv1: x [C,1,64,64] -> y1 [C,32,30,30], 5x5 stride 2, relu
// ---------------------------------------------------------------------------
__global__ __launch_bounds__(256) void conv1_k(
    const float* __restrict__ x, const float* __restrict__ w1,
    const float* __restrict__ b1, float* __restrict__ y1) {
  __shared__ float sIn[4096];
  __shared__ float sW[32 * 28];  // padded rows of 28 (25 used)
  __shared__ float sB[32];
  const int img = blockIdx.x;
  const int tid = threadIdx.x;
  {
    const float4* src = (const float4*)(x + (size_t)img * 4096);
    float4* dst = (float4*)sIn;
#pragma unroll
    for (int i = 0; i < 4; ++i) dst[tid + i * 256] = src[tid + i * 256];
  }
  for (int i = tid; i < 800; i += 256) {
    int ch = i / 25, k = i % 25;
    sW[ch * 28 + k] = w1[i];
  }
  if (tid < 32) sB[tid] = b1[tid];
  __syncthreads();
  float* out = y1 + (size_t)img * 28800;
#pragma unroll 1
  for (int it = 0; it < 2; ++it) {
    const int p0 = tid + it * 512;        // always < 900
    const int p1 = p0 + 256;
    const bool v1 = (p1 < 900);
    const int q1 = v1 ? p1 : 0;
    const int oy0 = p0 / 30, ox0 = p0 % 30;
    const int oy1 = q1 / 30, ox1 = q1 % 30;
    float a0[25], a1[25];
#pragma unroll
    for (int ky = 0; ky < 5; ++ky)
#pragma unroll
      for (int kx = 0; kx < 5; ++kx) {
        a0[ky * 5 + kx] = sIn[(2 * oy0 + ky) * 64 + 2 * ox0 + kx];
        a1[ky * 5 + kx] = sIn[(2 * oy1 + ky) * 64 + 2 * ox1 + kx];
      }
#pragma unroll 1
    for (int ch = 0; ch < 32; ++ch) {
      float acc0 = 0.f, acc1 = 0.f;
#pragma unroll
      for (int k = 0; k < 25; ++k) {
        const float w = sW[ch * 28 + k];
        acc0 += w * a0[k];
        acc1 += w * a1[k];
      }
      const float bb = sB[ch];
      out[ch * 900 + p0] = fmaxf(acc0 + bb, 0.f);
      if (v1) out[ch * 900 + p1] = fmaxf(acc1 + bb, 0.f);
    }
  }
}

// ---------------------------------------------------------------------------
// conv2 + maxpool: y1 [C,32,30,30] -> y2p [C,64,14,14]
// block: (rp in 0..6 -> out rows 4rp..4rp+3), img.  256 thr = 16 ocg x (r,cs)
// ---------------------------------------------------------------------------
__global__ __launch_bounds__(256) void conv2_k(
    const float* __restrict__ y1, const float* __restrict__ w2,
    const float* __restrict__ b2, float* __restrict__ y2p) {
  __shared__ float sIn[1440];   // [8 ic][6 rows][30]
  __shared__ float sW[6400];    // [64 och][100] (8*12 used)
  __shared__ float sOut[7168];  // [64 och][4 rows][28]
  const int rp = blockIdx.x;    // 0..6
  const int img = blockIdx.y;
  const int tid = threadIdx.x;
  const int ocg = tid >> 4;   // 0..15 -> och = ocg*4+oo
  const int low = tid & 15;
  const int r = low >> 2;     // 0..3 out row within quad
  const int cs = low & 3;     // cols 7cs..7cs+6
  const int row0 = rp * 4;
  float acc[4][7];
#pragma unroll
  for (int a = 0; a < 4; ++a)
#pragma unroll
    for (int p = 0; p < 7; ++p) acc[a][p] = 0.f;
  const float* y1img = y1 + (size_t)img * 28800;
  for (int icc = 0; icc < 4; ++icc) {
    __syncthreads();
    for (int idx = tid; idx < 1440; idx += 256) {
      int ic8 = idx / 180, rem = idx % 180;
      sIn[idx] = y1img[(icc * 8 + ic8) * 900 + row0 * 30 + rem];
    }
    for (int idx = tid; idx < 4608; idx += 256) {
      int och = idx / 72, rem = idx % 72;
      int ic8 = rem / 9, k = rem % 9;
      sW[och * 100 + ic8 * 12 + k] = w2[och * 288 + (icc * 8 + ic8) * 9 + k];
    }
    __syncthreads();
#pragma unroll 1
    for (int ic8 = 0; ic8 < 8; ++ic8) {
      float in[3][9];
#pragma unroll
      for (int ky = 0; ky < 3; ++ky)
#pragma unroll
        for (int j = 0; j < 9; ++j)
          in[ky][j] = sIn[ic8 * 180 + (r + ky) * 30 + cs * 7 + j];
#pragma unroll
      for (int oo = 0; oo < 4; ++oo) {
        const float* wp = &sW[(ocg * 4 + oo) * 100 + ic8 * 12];
#pragma unroll
        for (int ky = 0; ky < 3; ++ky) {
          const float w0 = wp[ky * 3 + 0];
          const float w1_ = wp[ky * 3 + 1];
          const float w2_ = wp[ky * 3 + 2];
#pragma unroll
          for (int p = 0; p < 7; ++p)
            acc[oo][p] += w0 * in[ky][p] + w1_ * in[ky][p + 1] + w2_ * in[ky][p + 2];
        }
      }
    }
  }
#pragma unroll
  for (int oo = 0; oo < 4; ++oo) {
    const float bb = b2[ocg * 4 + oo];
#pragma unroll
    for (int p = 0; p < 7; ++p)
      sOut[((ocg * 4 + oo) * 4 + r) * 28 + cs * 7 + p] = fmaxf(acc[oo][p] + bb, 0.f);
  }
  __syncthreads();
  float* outImg = y2p + (size_t)img * 12544;  // 64*196
  for (int idx = tid; idx < 1792; idx += 256) {
    int och = idx / 28, rem = idx % 28;
    int pr = rem / 14, pc = rem % 14;
    const float* s = &sOut[(och * 4 + pr * 2) * 28 + pc * 2];
    float m = fmaxf(fmaxf(s[0], s[1]), fmaxf(s[28], s[29]));
    outImg[och * 196 + (rp * 2 + pr) * 14 + pc] = m;
  }
}

// ---------------------------------------------------------------------------
// conv3: y2p [C,64,14,14] -> feats [C,96,12,12], relu
// block: (ochg in 0..1 -> 48 och), img.  256 thr = 16 ocg x 16 pos-groups(3x3)
// ---------------------------------------------------------------------------
__global__ __launch_bounds__(256) void conv3_k(
    const float* __restrict__ y2p, const float* __restrict__ w3,
    const float* __restrict__ b3, float* __restrict__ feats) {
  __shared__ float sIn[3136];  // [16 ic][196]
  __shared__ float sW[9408];   // [48 och][196] (16*12 used)
  const int ochg = blockIdx.x;  // 0..1
  const int img = blockIdx.y;
  const int tid = threadIdx.x;
  const int ocg = tid >> 4;  // 0..15 -> och = ochg*48 + ocg*3 + oo
  const int pg = tid & 15;
  const int pr = pg >> 2, pc = pg & 3;  // rows 3pr..3pr+2, cols 3pc..3pc+2
  float acc[3][9];
#pragma unroll
  for (int a = 0; a < 3; ++a)
#pragma unroll
    for (int p = 0; p < 9; ++p) acc[a][p] = 0.f;
  const float* inImg = y2p + (size_t)img * 12544;
  for (int icc = 0; icc < 4; ++icc) {
    __syncthreads();
    for (int idx = tid; idx < 3136; idx += 256)
      sIn[idx] = inImg[icc * 3136 + idx];
    for (int idx = tid; idx < 6912; idx += 256) {
      int och = idx / 144, rem = idx % 144;
      int ic = rem / 9, k = rem % 9;
      sW[och * 196 + ic * 12 + k] =
          w3[(size_t)(ochg * 48 + och) * 576 + (icc * 16 + ic) * 9 + k];
    }
    __syncthreads();
#pragma unroll 1
    for (int ic = 0; ic < 16; ++ic) {
      float in[5][5];
#pragma unroll
      for (int dy = 0; dy < 5; ++dy)
#pragma unroll
        for (int dx = 0; dx < 5; ++dx)
          in[dy][dx] = sIn[ic * 196 + (3 * pr + dy) * 14 + 3 * pc + dx];
#pragma unroll
      for (int oo = 0; oo < 3; ++oo) {
        const float* wp = &sW[(ocg * 3 + oo) * 196 + ic * 12];
#pragma unroll
        for (int ky = 0; ky < 3; ++ky)
#pragma unroll
          for (int kx = 0; kx < 3; ++kx) {
            const float w = wp[ky * 3 + kx];
#pragma unroll
            for (int py = 0; py < 3; ++py)
#pragma unroll
              for (int px = 0; px < 3; ++px)
                acc[oo][py * 3 + px] += w * in[py + ky][px + kx];
          }
      }
    }
  }
  float* outImg = feats + (size_t)img * 13824;
#pragma unroll
  for (int oo = 0; oo < 3; ++oo) {
    const int och = ochg * 48 + ocg * 3 + oo;
    const float bb = b3[och];
#pragma unroll
    for (int py = 0; py < 3; ++py)
#pragma unroll
      for (int px = 0; px < 3; ++px)
        outImg[och * 144 + (3 * pr + py) * 12 + 3 * pc + px] =
            fmaxf(acc[oo][py * 3 + px] + bb, 0.f);
  }
}

// ---------------------------------------------------------------------------
// ff GEMM (chunked): featsc [Cl,13824] x w_in[128,13824]^T
//   -> partials P[8][2048][128] at global rows frame0..frame0+Cl-1
// grid (ceil(Cl/64) mb, 8 kc); block 256; tile 64(M) x 128(N), ktile 32.
// ---------------------------------------------------------------------------
__global__ __launch_bounds__(256) void ffgemm_k(
    const float* __restrict__ A, const float* __restrict__ Bw,
    float* __restrict__ P, int frame0, int Cl) {
  __shared__ float sA[32 * 64];
  __shared__ float sB[32 * 128];
  const int mb = blockIdx.x;
  const int kc = blockIdx.y;  // 0..7
  const int tid = threadIdx.x;
  const int tm = tid >> 4, tn = tid & 15;
  const int m0 = tm * 4, n0 = tn * 8;
  float acc[4][8];
#pragma unroll
  for (int m = 0; m < 4; ++m)
#pragma unroll
    for (int n = 0; n < 8; ++n) acc[m][n] = 0.f;
  const int kbase = kc * 1728;
  for (int kt = 0; kt < 1728; kt += 32) {
    __syncthreads();
#pragma unroll
    for (int i = 0; i < 2; ++i) {
      int idx = tid + i * 256;
      int row = idx >> 3, kq = idx & 7;
      int rowc = mb * 64 + row;
      if (rowc >= Cl) rowc = Cl - 1;  // clamp (partial tile)
      float4 v = *(const float4*)(A + (size_t)rowc * 13824 + kbase + kt + kq * 4);
      sA[(kq * 4 + 0) * 64 + row] = v.x;
      sA[(kq * 4 + 1) * 64 + row] = v.y;
      sA[(kq * 4 + 2) * 64 + row] = v.z;
      sA[(kq * 4 + 3) * 64 + row] = v.w;
    }
#pragma unroll
    for (int i = 0; i < 4; ++i) {
      int idx = tid + i * 256;
      int n = idx >> 3, kq = idx & 7;
      float4 v = *(const float4*)(Bw + (size_t)n * 13824 + kbase + kt + kq * 4);
      sB[(kq * 4 + 0) * 128 + n] = v.x;
      sB[(kq * 4 + 1) * 128 + n] = v.y;
      sB[(kq * 4 + 2) * 128 + n] = v.z;
      sB[(kq * 4 + 3) * 128 + n] = v.w;
    }
    __syncthreads();
#pragma unroll
    for (int k = 0; k < 32; ++k) {
      float a4[4], b8[8];
      *(float4*)a4 = *(const float4*)&sA[k * 64 + m0];
      *(float4*)(b8) = *(const float4*)&sB[k * 128 + n0];
      *(float4*)(b8 + 4) = *(const float4*)&sB[k * 128 + n0 + 4];
#pragma unroll
      for (int m = 0; m < 4; ++m)
#pragma unroll
        for (int n = 0; n < 8; ++n) acc[m][n] += a4[m] * b8[n];
    }
  }
  float* Pp = P + ((size_t)kc * 2048 + (size_t)frame0 + (size_t)mb * 64) * 128;
#pragma unroll
  for (int m = 0; m < 4; ++m) {
    if (mb * 64 + m0 + m < Cl) {
      *(float4*)&Pp[(m0 + m) * 128 + n0] = *(float4*)&acc[m][0];
      *(float4*)&Pp[(m0 + m) * 128 + n0 + 4] = *(float4*)&acc[m][4];
    }
  }
}

__global__ __launch_bounds__(256) void ffreduce_k(const float* __restrict__ P,
                                                  float* __restrict__ ffo) {
  const int i = blockIdx.x * 256 + threadIdx.x;  // 262144 total
  float s = 0.f;
#pragma unroll
  for (int kcc = 0; kcc < 8; ++kcc) s += P[(size_t)kcc * 262144 + i];
  ffo[i] = s;
}

// ---------------------------------------------------------------------------
// Recurrent LIF scan: one wave (64 thr) per batch item; each thread owns
// neurons h=t and h=t+64. Spikes as wave-uniform ballot masks; sparse matvec.
// ---------------------------------------------------------------------------
__global__ __launch_bounds__(64) void scan_k(
    const float* __restrict__ ff, const float* __restrict__ w_rec,
    const float* __restrict__ w_fc, const float* __restrict__ b_fc,
    float* __restrict__ out) {
#pragma clang fp contract(off)
  __shared__ float sWr[16384];  // sWr[j*128+h] = w_rec[h][j]  (64 KB)
  const int b = blockIdx.x;
  const int t = threadIdx.x;  // 0..63
  for (int idx = t; idx < 16384; idx += 64) {
    int hh = idx >> 7, j = idx & 127;
    sWr[j * 128 + hh] = w_rec[idx];
  }
  float wf0[10], wf1[10], bf[10];
#pragma unroll
  for (int c = 0; c < 10; ++c) {
    wf0[c] = w_fc[c * 128 + t];
    wf1[c] = w_fc[c * 128 + 64 + t];
    bf[c] = b_fc[c];
  }
  __syncthreads();
  float v0 = 0.f, v1 = 0.f, i0 = 0.f, i1 = 0.f;
  float vr[10], ir[10], vmax[10];
#pragma unroll
  for (int c = 0; c < 10; ++c) {
    vr[c] = 0.f;
    ir[c] = 0.f;
    vmax[c] = -1e30f;
  }
  unsigned long long pm0 = 0ull, pm1 = 0ull;
  const float* ffb = ff + (size_t)b * 8192;
#pragma unroll 1
  for (int ts = 0; ts < 64; ++ts) {
    const float vd0 = v0 + 0.1f * (i0 - v0);
    const float vd1 = v1 + 0.1f * (i1 - v1);
    const float id0 = i0 - 0.2f * i0;
    const float id1 = i1 - 0.2f * i1;
    const bool z0 = (vd0 - 0.4f) > 0.f;
    const bool z1 = (vd1 - 0.4f) > 0.f;
    v0 = z0 ? 0.f : vd0;
    v1 = z1 ? 0.f : vd1;
    float rec0 = 0.f, rec1 = 0.f;
    unsigned long long mm = pm0;
    while (mm) {
      int j = __ffsll(mm) - 1;
      mm &= mm - 1;
      rec0 += sWr[j * 128 + t];
      rec1 += sWr[j * 128 + t + 64];
    }
    mm = pm1;
    while (mm) {
      int j = __ffsll(mm) - 1;
      mm &= mm - 1;
      rec0 += sWr[(j + 64) * 128 + t];
      rec1 += sWr[(j + 64) * 128 + t + 64];
    }
    i0 = (id0 + ffb[ts * 128 + t]) + rec0;
    i1 = (id1 + ffb[ts * 128 + 64 + t]) + rec1;
    pm0 = __ballot(z0);
    pm1 = __ballot(z1);
#pragma unroll
    for (int c = 0; c < 10; ++c) {
      float val = (z0 ? wf0[c] : 0.f) + (z1 ? wf1[c] : 0.f);
      val += __shfl_xor(val, 1);
      val += __shfl_xor(val, 2);
      val += __shfl_xor(val, 4);
      val += __shfl_xor(val, 8);
      val += __shfl_xor(val, 16);
      val += __shfl_xor(val, 32);
      const float ro = val + bf[c];
      vr[c] = vr[c] + 0.1f * (ir[c] - vr[c]);
      vmax[c] = fmaxf(vmax[c], vr[c]);
      ir[c] = (ir[c] - 0.2f * ir[c]) + ro;
    }
  }
  if (t == 0) {
    float M = vmax[0];
#pragma unroll
    for (int c = 1; c < 10; ++c) M = fmaxf(M, vmax[c]);
    float s = 0.f;
#pragma unroll
    for (int c = 0; c < 10; ++c) s += expf(vmax[c] - M);
    const float ls = logf(s);
#pragma unroll
    for (int c = 0; c < 10; ++c) out[b * 10 + c] = vmax[c] - M - ls;
  }
}

// ---------------------------------------------------------------------------
extern "C" void kernel_launch(void* const* d_in, const int* in_sizes, int n_in,
                              void* d_out, int out_size, void* d_ws,
                              size_t ws_size, hipStream_t stream) {
  (void)in_sizes;
  (void)n_in;
  (void)out_size;
  const float* x = (const float*)d_in[0];
  const float* w1 = (const float*)d_in[1];
  const float* b1 = (const float*)d_in[2];
  const float* w2 = (const float*)d_in[3];
  const float* b2 = (const float*)d_in[4];
  const float* w3 = (const float*)d_in[5];
  const float* b3 = (const float*)d_in[6];
  const float* w_in = (const float*)d_in[7];
  const float* w_rec = (const float*)d_in[8];
  const float* w_fc = (const float*)d_in[9];
  const float* b_fc = (const float*)d_in[10];
  float* out = (float*)d_out;
  char* ws = (char*)d_ws;

  // --- workspace plan, sized to ws_size (deterministic function of it) ----
  // header: ff [2048][128] (1 MB) + P [8][2048][128] (8 MB)
  // per-frame chunk buffers: y1 115200 B + y2p 50176 B + feats 55296 B
  const size_t HDR = 1048576ull + 8388608ull;     // 9,437,184
  const size_t PERF = 115200ull + 50176ull + 55296ull;  // 220,672
  int C = 32;
  for (int c = 2048; c >= 32; c >>= 1) {
    if (HDR + (size_t)c * PERF <= ws_size) { C = c; break; }
  }
  float* ffbuf = (float*)ws;
  float* P = (float*)(ws + 1048576ull);
  float* y1c = (float*)(ws + HDR);
  float* y2c = y1c + (size_t)C * 28800;
  float* fc = y2c + (size_t)C * 12544;

  const int nChunks = 2048 / C;
  const int mbN = (C + 63) / 64;
  for (int ch = 0; ch < nChunks; ++ch) {
    const int f0 = ch * C;
    conv1_k<<<C, 256, 0, stream>>>(x + (size_t)f0 * 4096, w1, b1, y1c);
    conv2_k<<<dim3(7, C), 256, 0, stream>>>(y1c, w2, b2, y2c);
    conv3_k<<<dim3(2, C), 256, 0, stream>>>(y2c, w3, b3, fc);
    ffgemm_k<<<dim3(mbN, 8), 256, 0, stream>>>(fc, w_in, P, f0, C);
  }
  ffreduce_k<<<1024, 256, 0, stream>>>(P, ffbuf);
  scan_k<<<32, 64, 0, stream>>>(ffbuf, w_rec, w_fc, b_fc, out);
}

// Round 3
// 1519.058 us; speedup vs baseline: 1.9564x; 1.9564x over previous
//
#include <hip/hip_runtime.h>
#include <math.h>

typedef _Float16 half8 __attribute__((ext_vector_type(8)));
typedef float f32x16 __attribute__((ext_vector_type(16)));

// ---------------------------------------------------------------------------
// conv1: x [C,1,64,64] -> y1 [C,32,30,30], 5x5 stride 2, relu
// ---------------------------------------------------------------------------
__global__ __launch_bounds__(256) void conv1_k(
    const float* __restrict__ x, const float* __restrict__ w1,
    const float* __restrict__ b1, float* __restrict__ y1) {
  __shared__ float sIn[4096];
  __shared__ float sW[32 * 28];
  __shared__ float sB[32];
  const int img = blockIdx.x;
  const int tid = threadIdx.x;
  {
    const float4* src = (const float4*)(x + (size_t)img * 4096);
    float4* dst = (float4*)sIn;
#pragma unroll
    for (int i = 0; i < 4; ++i) dst[tid + i * 256] = src[tid + i * 256];
  }
  for (int i = tid; i < 800; i += 256) {
    int ch = i / 25, k = i % 25;
    sW[ch * 28 + k] = w1[i];
  }
  if (tid < 32) sB[tid] = b1[tid];
  __syncthreads();
  float* out = y1 + (size_t)img * 28800;
#pragma unroll 1
  for (int it = 0; it < 2; ++it) {
    const int p0 = tid + it * 512;
    const int p1 = p0 + 256;
    const bool v1 = (p1 < 900);
    const int q1 = v1 ? p1 : 0;
    const int oy0 = p0 / 30, ox0 = p0 % 30;
    const int oy1 = q1 / 30, ox1 = q1 % 30;
    float a0[25], a1[25];
#pragma unroll
    for (int ky = 0; ky < 5; ++ky)
#pragma unroll
      for (int kx = 0; kx < 5; ++kx) {
        a0[ky * 5 + kx] = sIn[(2 * oy0 + ky) * 64 + 2 * ox0 + kx];
        a1[ky * 5 + kx] = sIn[(2 * oy1 + ky) * 64 + 2 * ox1 + kx];
      }
#pragma unroll 1
    for (int ch = 0; ch < 32; ++ch) {
      float acc0 = 0.f, acc1 = 0.f;
#pragma unroll
      for (int k = 0; k < 25; ++k) {
        const float w = sW[ch * 28 + k];
        acc0 += w * a0[k];
        acc1 += w * a1[k];
      }
      const float bb = sB[ch];
      out[ch * 900 + p0] = fmaxf(acc0 + bb, 0.f);
      if (v1) out[ch * 900 + p1] = fmaxf(acc1 + bb, 0.f);
    }
  }
}

// ---------------------------------------------------------------------------
// conv2 + maxpool via MFMA split-f16 implicit GEMM.
// y1 [C,32,30,30] -> y2p [C,64,14,14]
// grid (7 rp, C/2 image-pairs); 448 thr = 7 waves.
// M = 224 positions (2 img x 4 conv rows x 28 cols) = 7 m-tiles of 32
// N = 64 och = 2 n-tiles of 32;  K per tap = 32 ic = 2 MFMA k-steps.
// Split: x ~= xh + xl/1024 (f16);  Y = acc(hh) + acc(hl+lh)/1024.
// LDS 64KB: Xh[0,12288) Xl[12288,24576) Wh[24576,28672) Wl[28672,32768)
// ---------------------------------------------------------------------------
__global__ __launch_bounds__(448) void conv2_mfma_k(
    const float* __restrict__ y1, const float* __restrict__ w2,
    const float* __restrict__ b2, float* __restrict__ y2p) {
  __shared__ __align__(16) _Float16 S[32768];
  const int rp = blockIdx.x;
  const int img0 = blockIdx.y * 2;
  const int tid = threadIdx.x;
  const int row0 = rp * 4;

  // ---- stage X: 2 img x 32 ic x 6 rows x 30 cols, fp32 -> split f16 ----
  for (int idx = tid; idx < 11520; idx += 448) {
    const int img = idx / 5760;
    int rem = idx - img * 5760;
    const int ic = rem / 180;
    rem -= ic * 180;
    const int row = rem / 30;
    const int col = rem - row * 30;
    const float v =
        y1[((size_t)(img0 + img) * 32 + ic) * 900 + (row0 + row) * 30 + col];
    const _Float16 h = (_Float16)v;
    const _Float16 l = (_Float16)((v - (float)h) * 1024.0f);
    const int icsw = ic ^ (((col >> 1) & 3) << 3);  // bank swizzle
    const int base = img * 6144 + (row * 32 + col) * 32 + icsw;
    S[base] = h;
    S[12288 + base] = l;
  }

  const int w = tid >> 6;   // wave 0..6 -> m-tile
  const int lane = tid & 63;
  const int l31 = lane & 31;
  const int g = lane >> 5;  // 0/1
  const int m = w * 32 + l31;          // position 0..223
  const int aimg = m / 112;
  const int apos = m - aimg * 112;
  const int ar = apos / 28;
  const int ax = apos - ar * 28;
  const int icg = g * 8;
  const int swzB = ((l31 >> 1) & 3) << 3;

  f32x16 acc00 = {}, acc01 = {}, acc10 = {}, acc11 = {};

#pragma unroll 1
  for (int tc = 0; tc < 5; ++tc) {
    __syncthreads();
    // ---- stage W chunk (taps 2tc .. 2tc+ntaps-1) ----
    if (tc < 4) {
      for (int idx = tid; idx < 4096; idx += 448) {
        const int och = idx >> 6;
        const int rem = idx & 63;
        const int ic = rem >> 1;
        const int tl = rem & 1;
        const float v = w2[och * 288 + ic * 9 + tc * 2 + tl];
        const _Float16 h = (_Float16)v;
        const _Float16 l = (_Float16)((v - (float)h) * 1024.0f);
        const int icsw = ic ^ (((och >> 1) & 3) << 3);
        const int o = (tl * 64 + och) * 32 + icsw;
        S[24576 + o] = h;
        S[28672 + o] = l;
      }
    } else {
      for (int idx = tid; idx < 2048; idx += 448) {
        const int och = idx >> 5;
        const int ic = idx & 31;
        const float v = w2[och * 288 + ic * 9 + 8];
        const _Float16 h = (_Float16)v;
        const _Float16 l = (_Float16)((v - (float)h) * 1024.0f);
        const int icsw = ic ^ (((och >> 1) & 3) << 3);
        const int o = och * 32 + icsw;
        S[24576 + o] = h;
        S[28672 + o] = l;
      }
    }
    __syncthreads();
    const int ntaps = (tc == 4) ? 1 : 2;
#pragma unroll 1
    for (int tl = 0; tl < ntaps; ++tl) {
      const int tap = tc * 2 + tl;
      const int ky = tap / 3;
      const int kx = tap - ky * 3;
      const int acol = ax + kx;
      const int swzA = ((acol >> 1) & 3) << 3;
      const int abase = aimg * 6144 + ((ar + ky) * 32 + acol) * 32;
      const int bbase0 = 24576 + (tl * 64 + l31) * 32;
      const int bbase1 = bbase0 + 32 * 32;
#pragma unroll
      for (int s = 0; s < 2; ++s) {
        const int icoA = (s * 16 + icg) ^ swzA;
        const int icoB = (s * 16 + icg) ^ swzB;
        half8 ah = *(const half8*)&S[abase + icoA];
        half8 al = *(const half8*)&S[12288 + abase + icoA];
        half8 bh0 = *(const half8*)&S[bbase0 + icoB];
        half8 bl0 = *(const half8*)&S[4096 + bbase0 + icoB];
        half8 bh1 = *(const half8*)&S[bbase1 + icoB];
        half8 bl1 = *(const half8*)&S[4096 + bbase1 + icoB];
        acc00 = __builtin_amdgcn_mfma_f32_32x32x16_f16(ah, bh0, acc00, 0, 0, 0);
        acc10 = __builtin_amdgcn_mfma_f32_32x32x16_f16(ah, bl0, acc10, 0, 0, 0);
        acc10 = __builtin_amdgcn_mfma_f32_32x32x16_f16(al, bh0, acc10, 0, 0, 0);
        acc01 = __builtin_amdgcn_mfma_f32_32x32x16_f16(ah, bh1, acc01, 0, 0, 0);
        acc11 = __builtin_amdgcn_mfma_f32_32x32x16_f16(ah, bl1, acc11, 0, 0, 0);
        acc11 = __builtin_amdgcn_mfma_f32_32x32x16_f16(al, bh1, acc11, 0, 0, 0);
      }
    }
  }
  __syncthreads();
  // ---- write conv outputs (fp32) to LDS for pooling ----
  float* sPool = (float*)S;  // [224 pos][64 och] = 57344 B
#pragma unroll
  for (int r = 0; r < 16; ++r) {
    const int mrow = (r & 3) + 8 * (r >> 2) + 4 * g;
    const int mo = w * 32 + mrow;
    sPool[mo * 64 + l31] = acc00[r] + acc10[r] * 9.765625e-4f;
    sPool[mo * 64 + 32 + l31] = acc01[r] + acc11[r] * 9.765625e-4f;
  }
  __syncthreads();
  // ---- bias + relu + 2x2 maxpool + store ----
  for (int idx = tid; idx < 3584; idx += 448) {
    const int img = idx / 1792;
    int rem = idx - img * 1792;
    const int och = rem / 28;
    rem -= och * 28;
    const int pr = rem / 14;
    const int pc = rem - pr * 14;
    const int mb = img * 112 + pr * 56 + pc * 2;
    const float a = sPool[mb * 64 + och];
    const float b = sPool[(mb + 1) * 64 + och];
    const float c = sPool[(mb + 28) * 64 + och];
    const float d = sPool[(mb + 29) * 64 + och];
    const float mx = fmaxf(fmaxf(a, b), fmaxf(c, d));
    y2p[((size_t)(img0 + img) * 64 + och) * 196 + (rp * 2 + pr) * 14 + pc] =
        fmaxf(mx + b2[och], 0.f);
  }
}

// ---------------------------------------------------------------------------
// conv3: y2p [C,64,14,14] -> feats [C,96,12,12], relu
// ---------------------------------------------------------------------------
__global__ __launch_bounds__(256) void conv3_k(
    const float* __restrict__ y2p, const float* __restrict__ w3,
    const float* __restrict__ b3, float* __restrict__ feats) {
  __shared__ float sIn[3136];
  __shared__ float sW[9408];
  const int ochg = blockIdx.x;
  const int img = blockIdx.y;
  const int tid = threadIdx.x;
  const int ocg = tid >> 4;
  const int pg = tid & 15;
  const int pr = pg >> 2, pc = pg & 3;
  float acc[3][9];
#pragma unroll
  for (int a = 0; a < 3; ++a)
#pragma unroll
    for (int p = 0; p < 9; ++p) acc[a][p] = 0.f;
  const float* inImg = y2p + (size_t)img * 12544;
  for (int icc = 0; icc < 4; ++icc) {
    __syncthreads();
    for (int idx = tid; idx < 3136; idx += 256)
      sIn[idx] = inImg[icc * 3136 + idx];
    for (int idx = tid; idx < 6912; idx += 256) {
      int och = idx / 144, rem = idx % 144;
      int ic = rem / 9, k = rem % 9;
      sW[och * 196 + ic * 12 + k] =
          w3[(size_t)(ochg * 48 + och) * 576 + (icc * 16 + ic) * 9 + k];
    }
    __syncthreads();
#pragma unroll 1
    for (int ic = 0; ic < 16; ++ic) {
      float in[5][5];
#pragma unroll
      for (int dy = 0; dy < 5; ++dy)
#pragma unroll
        for (int dx = 0; dx < 5; ++dx)
          in[dy][dx] = sIn[ic * 196 + (3 * pr + dy) * 14 + 3 * pc + dx];
#pragma unroll
      for (int oo = 0; oo < 3; ++oo) {
        const float* wp = &sW[(ocg * 3 + oo) * 196 + ic * 12];
#pragma unroll
        for (int ky = 0; ky < 3; ++ky)
#pragma unroll
          for (int kx = 0; kx < 3; ++kx) {
            const float w = wp[ky * 3 + kx];
#pragma unroll
            for (int py = 0; py < 3; ++py)
#pragma unroll
              for (int px = 0; px < 3; ++px)
                acc[oo][py * 3 + px] += w * in[py + ky][px + kx];
          }
      }
    }
  }
  float* outImg = feats + (size_t)img * 13824;
#pragma unroll
  for (int oo = 0; oo < 3; ++oo) {
    const int och = ochg * 48 + ocg * 3 + oo;
    const float bb = b3[och];
#pragma unroll
    for (int py = 0; py < 3; ++py)
#pragma unroll
      for (int px = 0; px < 3; ++px)
        outImg[och * 144 + (3 * pr + py) * 12 + 3 * pc + px] =
            fmaxf(acc[oo][py * 3 + px] + bb, 0.f);
  }
}

// ---------------------------------------------------------------------------
// ff GEMM (chunked): featsc [Cl,13824] x w_in[128,13824]^T -> P[8][2048][128]
// ---------------------------------------------------------------------------
__global__ __launch_bounds__(256) void ffgemm_k(
    const float* __restrict__ A, const float* __restrict__ Bw,
    float* __restrict__ P, int frame0, int Cl) {
  __shared__ float sA[32 * 64];
  __shared__ float sB[32 * 128];
  const int mb = blockIdx.x;
  const int kc = blockIdx.y;
  const int tid = threadIdx.x;
  const int tm = tid >> 4, tn = tid & 15;
  const int m0 = tm * 4, n0 = tn * 8;
  float acc[4][8];
#pragma unroll
  for (int m = 0; m < 4; ++m)
#pragma unroll
    for (int n = 0; n < 8; ++n) acc[m][n] = 0.f;
  const int kbase = kc * 1728;
  for (int kt = 0; kt < 1728; kt += 32) {
    __syncthreads();
#pragma unroll
    for (int i = 0; i < 2; ++i) {
      int idx = tid + i * 256;
      int row = idx >> 3, kq = idx & 7;
      int rowc = mb * 64 + row;
      if (rowc >= Cl) rowc = Cl - 1;
      float4 v = *(const float4*)(A + (size_t)rowc * 13824 + kbase + kt + kq * 4);
      sA[(kq * 4 + 0) * 64 + row] = v.x;
      sA[(kq * 4 + 1) * 64 + row] = v.y;
      sA[(kq * 4 + 2) * 64 + row] = v.z;
      sA[(kq * 4 + 3) * 64 + row] = v.w;
    }
#pragma unroll
    for (int i = 0; i < 4; ++i) {
      int idx = tid + i * 256;
      int n = idx >> 3, kq = idx & 7;
      float4 v = *(const float4*)(Bw + (size_t)n * 13824 + kbase + kt + kq * 4);
      sB[(kq * 4 + 0) * 128 + n] = v.x;
      sB[(kq * 4 + 1) * 128 + n] = v.y;
      sB[(kq * 4 + 2) * 128 + n] = v.z;
      sB[(kq * 4 + 3) * 128 + n] = v.w;
    }
    __syncthreads();
#pragma unroll
    for (int k = 0; k < 32; ++k) {
      float a4[4], b8[8];
      *(float4*)a4 = *(const float4*)&sA[k * 64 + m0];
      *(float4*)(b8) = *(const float4*)&sB[k * 128 + n0];
      *(float4*)(b8 + 4) = *(const float4*)&sB[k * 128 + n0 + 4];
#pragma unroll
      for (int m = 0; m < 4; ++m)
#pragma unroll
        for (int n = 0; n < 8; ++n) acc[m][n] += a4[m] * b8[n];
    }
  }
  float* Pp = P + ((size_t)kc * 2048 + (size_t)frame0 + (size_t)mb * 64) * 128;
#pragma unroll
  for (int m = 0; m < 4; ++m) {
    if (mb * 64 + m0 + m < Cl) {
      *(float4*)&Pp[(m0 + m) * 128 + n0] = *(float4*)&acc[m][0];
      *(float4*)&Pp[(m0 + m) * 128 + n0 + 4] = *(float4*)&acc[m][4];
    }
  }
}

__global__ __launch_bounds__(256) void ffreduce_k(const float* __restrict__ P,
                                                  float* __restrict__ ffo) {
  const int i = blockIdx.x * 256 + threadIdx.x;
  float s = 0.f;
#pragma unroll
  for (int kcc = 0; kcc < 8; ++kcc) s += P[(size_t)kcc * 262144 + i];
  ffo[i] = s;
}

// ---------------------------------------------------------------------------
// Recurrent LIF scan (unchanged from R2 — bit-exact baseline)
// ---------------------------------------------------------------------------
__global__ __launch_bounds__(64) void scan_k(
    const float* __restrict__ ff, const float* __restrict__ w_rec,
    const float* __restrict__ w_fc, const float* __restrict__ b_fc,
    float* __restrict__ out) {
#pragma clang fp contract(off)
  __shared__ float sWr[16384];
  const int b = blockIdx.x;
  const int t = threadIdx.x;
  for (int idx = t; idx < 16384; idx += 64) {
    int hh = idx >> 7, j = idx & 127;
    sWr[j * 128 + hh] = w_rec[idx];
  }
  float wf0[10], wf1[10], bf[10];
#pragma unroll
  for (int c = 0; c < 10; ++c) {
    wf0[c] = w_fc[c * 128 + t];
    wf1[c] = w_fc[c * 128 + 64 + t];
    bf[c] = b_fc[c];
  }
  __syncthreads();
  float v0 = 0.f, v1 = 0.f, i0 = 0.f, i1 = 0.f;
  float vr[10], ir[10], vmax[10];
#pragma unroll
  for (int c = 0; c < 10; ++c) {
    vr[c] = 0.f;
    ir[c] = 0.f;
    vmax[c] = -1e30f;
  }
  unsigned long long pm0 = 0ull, pm1 = 0ull;
  const float* ffb = ff + (size_t)b * 8192;
#pragma unroll 1
  for (int ts = 0; ts < 64; ++ts) {
    const float vd0 = v0 + 0.1f * (i0 - v0);
    const float vd1 = v1 + 0.1f * (i1 - v1);
    const float id0 = i0 - 0.2f * i0;
    const float id1 = i1 - 0.2f * i1;
    const bool z0 = (vd0 - 0.4f) > 0.f;
    const bool z1 = (vd1 - 0.4f) > 0.f;
    v0 = z0 ? 0.f : vd0;
    v1 = z1 ? 0.f : vd1;
    float rec0 = 0.f, rec1 = 0.f;
    unsigned long long mm = pm0;
    while (mm) {
      int j = __ffsll(mm) - 1;
      mm &= mm - 1;
      rec0 += sWr[j * 128 + t];
      rec1 += sWr[j * 128 + t + 64];
    }
    mm = pm1;
    while (mm) {
      int j = __ffsll(mm) - 1;
      mm &= mm - 1;
      rec0 += sWr[(j + 64) * 128 + t];
      rec1 += sWr[(j + 64) * 128 + t + 64];
    }
    i0 = (id0 + ffb[ts * 128 + t]) + rec0;
    i1 = (id1 + ffb[ts * 128 + 64 + t]) + rec1;
    pm0 = __ballot(z0);
    pm1 = __ballot(z1);
#pragma unroll
    for (int c = 0; c < 10; ++c) {
      float val = (z0 ? wf0[c] : 0.f) + (z1 ? wf1[c] : 0.f);
      val += __shfl_xor(val, 1);
      val += __shfl_xor(val, 2);
      val += __shfl_xor(val, 4);
      val += __shfl_xor(val, 8);
      val += __shfl_xor(val, 16);
      val += __shfl_xor(val, 32);
      const float ro = val + bf[c];
      vr[c] = vr[c] + 0.1f * (ir[c] - vr[c]);
      vmax[c] = fmaxf(vmax[c], vr[c]);
      ir[c] = (ir[c] - 0.2f * ir[c]) + ro;
    }
  }
  if (t == 0) {
    float M = vmax[0];
#pragma unroll
    for (int c = 1; c < 10; ++c) M = fmaxf(M, vmax[c]);
    float s = 0.f;
#pragma unroll
    for (int c = 0; c < 10; ++c) s += expf(vmax[c] - M);
    const float ls = logf(s);
#pragma unroll
    for (int c = 0; c < 10; ++c) out[b * 10 + c] = vmax[c] - M - ls;
  }
}

// ---------------------------------------------------------------------------
extern "C" void kernel_launch(void* const* d_in, const int* in_sizes, int n_in,
                              void* d_out, int out_size, void* d_ws,
                              size_t ws_size, hipStream_t stream) {
  (void)in_sizes;
  (void)n_in;
  (void)out_size;
  const float* x = (const float*)d_in[0];
  const float* w1 = (const float*)d_in[1];
  const float* b1 = (const float*)d_in[2];
  const float* w2 = (const float*)d_in[3];
  const float* b2 = (const float*)d_in[4];
  const float* w3 = (const float*)d_in[5];
  const float* b3 = (const float*)d_in[6];
  const float* w_in = (const float*)d_in[7];
  const float* w_rec = (const float*)d_in[8];
  const float* w_fc = (const float*)d_in[9];
  const float* b_fc = (const float*)d_in[10];
  float* out = (float*)d_out;
  char* ws = (char*)d_ws;

  const size_t HDR = 1048576ull + 8388608ull;
  const size_t PERF = 115200ull + 50176ull + 55296ull;
  int C = 32;
  for (int c = 2048; c >= 32; c >>= 1) {
    if (HDR + (size_t)c * PERF <= ws_size) { C = c; break; }
  }
  float* ffbuf = (float*)ws;
  float* P = (float*)(ws + 1048576ull);
  float* y1c = (float*)(ws + HDR);
  float* y2c = y1c + (size_t)C * 28800;
  float* fc = y2c + (size_t)C * 12544;

  const int nChunks = 2048 / C;
  const int mbN = (C + 63) / 64;
  for (int ch = 0; ch < nChunks; ++ch) {
    const int f0 = ch * C;
    conv1_k<<<C, 256, 0, stream>>>(x + (size_t)f0 * 4096, w1, b1, y1c);
    conv2_mfma_k<<<dim3(7, C / 2), 448, 0, stream>>>(y1c, w2, b2, y2c);
    conv3_k<<<dim3(2, C), 256, 0, stream>>>(y2c, w3, b3, fc);
    ffgemm_k<<<dim3(mbN, 8), 256, 0, stream>>>(fc, w_in, P, f0, C);
  }
  ffreduce_k<<<1024, 256, 0, stream>>>(P, ffbuf);
  scan_k<<<32, 64, 0, stream>>>(ffbuf, w_rec, w_fc, b_fc, out);
}

// Round 4
// 1506.069 us; speedup vs baseline: 1.9732x; 1.0086x over previous
//
#include <hip/hip_runtime.h>
#include <math.h>

typedef _Float16 half8 __attribute__((ext_vector_type(8)));
typedef float f32x16 __attribute__((ext_vector_type(16)));

// ---------------------------------------------------------------------------
// conv1: x [C,1,64,64] -> y1 [C,32,30,30], 5x5 stride 2, relu
// ---------------------------------------------------------------------------
__global__ __launch_bounds__(256) void conv1_k(
    const float* __restrict__ x, const float* __restrict__ w1,
    const float* __restrict__ b1, float* __restrict__ y1) {
  __shared__ float sIn[4096];
  __shared__ float sW[32 * 28];
  __shared__ float sB[32];
  const int img = blockIdx.x;
  const int tid = threadIdx.x;
  {
    const float4* src = (const float4*)(x + (size_t)img * 4096);
    float4* dst = (float4*)sIn;
#pragma unroll
    for (int i = 0; i < 4; ++i) dst[tid + i * 256] = src[tid + i * 256];
  }
  for (int i = tid; i < 800; i += 256) {
    int ch = i / 25, k = i % 25;
    sW[ch * 28 + k] = w1[i];
  }
  if (tid < 32) sB[tid] = b1[tid];
  __syncthreads();
  float* out = y1 + (size_t)img * 28800;
#pragma unroll 1
  for (int it = 0; it < 2; ++it) {
    const int p0 = tid + it * 512;
    const int p1 = p0 + 256;
    const bool v1 = (p1 < 900);
    const int q1 = v1 ? p1 : 0;
    const int oy0 = p0 / 30, ox0 = p0 % 30;
    const int oy1 = q1 / 30, ox1 = q1 % 30;
    float a0[25], a1[25];
#pragma unroll
    for (int ky = 0; ky < 5; ++ky)
#pragma unroll
      for (int kx = 0; kx < 5; ++kx) {
        a0[ky * 5 + kx] = sIn[(2 * oy0 + ky) * 64 + 2 * ox0 + kx];
        a1[ky * 5 + kx] = sIn[(2 * oy1 + ky) * 64 + 2 * ox1 + kx];
      }
#pragma unroll 1
    for (int ch = 0; ch < 32; ++ch) {
      float acc0 = 0.f, acc1 = 0.f;
#pragma unroll
      for (int k = 0; k < 25; ++k) {
        const float w = sW[ch * 28 + k];
        acc0 += w * a0[k];
        acc1 += w * a1[k];
      }
      const float bb = sB[ch];
      out[ch * 900 + p0] = fmaxf(acc0 + bb, 0.f);
      if (v1) out[ch * 900 + p1] = fmaxf(acc1 + bb, 0.f);
    }
  }
}

// ---------------------------------------------------------------------------
// conv2 + maxpool via MFMA split-f16 implicit GEMM (unchanged from R3).
// ---------------------------------------------------------------------------
__global__ __launch_bounds__(448) void conv2_mfma_k(
    const float* __restrict__ y1, const float* __restrict__ w2,
    const float* __restrict__ b2, float* __restrict__ y2p) {
  __shared__ __align__(16) _Float16 S[32768];
  const int rp = blockIdx.x;
  const int img0 = blockIdx.y * 2;
  const int tid = threadIdx.x;
  const int row0 = rp * 4;

  for (int idx = tid; idx < 11520; idx += 448) {
    const int img = idx / 5760;
    int rem = idx - img * 5760;
    const int ic = rem / 180;
    rem -= ic * 180;
    const int row = rem / 30;
    const int col = rem - row * 30;
    const float v =
        y1[((size_t)(img0 + img) * 32 + ic) * 900 + (row0 + row) * 30 + col];
    const _Float16 h = (_Float16)v;
    const _Float16 l = (_Float16)((v - (float)h) * 1024.0f);
    const int icsw = ic ^ (((col >> 1) & 3) << 3);
    const int base = img * 6144 + (row * 32 + col) * 32 + icsw;
    S[base] = h;
    S[12288 + base] = l;
  }

  const int w = tid >> 6;
  const int lane = tid & 63;
  const int l31 = lane & 31;
  const int g = lane >> 5;
  const int m = w * 32 + l31;
  const int aimg = m / 112;
  const int apos = m - aimg * 112;
  const int ar = apos / 28;
  const int ax = apos - ar * 28;
  const int icg = g * 8;
  const int swzB = ((l31 >> 1) & 3) << 3;

  f32x16 acc00 = {}, acc01 = {}, acc10 = {}, acc11 = {};

#pragma unroll 1
  for (int tc = 0; tc < 5; ++tc) {
    __syncthreads();
    if (tc < 4) {
      for (int idx = tid; idx < 4096; idx += 448) {
        const int och = idx >> 6;
        const int rem = idx & 63;
        const int ic = rem >> 1;
        const int tl = rem & 1;
        const float v = w2[och * 288 + ic * 9 + tc * 2 + tl];
        const _Float16 h = (_Float16)v;
        const _Float16 l = (_Float16)((v - (float)h) * 1024.0f);
        const int icsw = ic ^ (((och >> 1) & 3) << 3);
        const int o = (tl * 64 + och) * 32 + icsw;
        S[24576 + o] = h;
        S[28672 + o] = l;
      }
    } else {
      for (int idx = tid; idx < 2048; idx += 448) {
        const int och = idx >> 5;
        const int ic = idx & 31;
        const float v = w2[och * 288 + ic * 9 + 8];
        const _Float16 h = (_Float16)v;
        const _Float16 l = (_Float16)((v - (float)h) * 1024.0f);
        const int icsw = ic ^ (((och >> 1) & 3) << 3);
        const int o = och * 32 + icsw;
        S[24576 + o] = h;
        S[28672 + o] = l;
      }
    }
    __syncthreads();
    const int ntaps = (tc == 4) ? 1 : 2;
#pragma unroll 1
    for (int tl = 0; tl < ntaps; ++tl) {
      const int tap = tc * 2 + tl;
      const int ky = tap / 3;
      const int kx = tap - ky * 3;
      const int acol = ax + kx;
      const int swzA = ((acol >> 1) & 3) << 3;
      const int abase = aimg * 6144 + ((ar + ky) * 32 + acol) * 32;
      const int bbase0 = 24576 + (tl * 64 + l31) * 32;
      const int bbase1 = bbase0 + 32 * 32;
#pragma unroll
      for (int s = 0; s < 2; ++s) {
        const int icoA = (s * 16 + icg) ^ swzA;
        const int icoB = (s * 16 + icg) ^ swzB;
        half8 ah = *(const half8*)&S[abase + icoA];
        half8 al = *(const half8*)&S[12288 + abase + icoA];
        half8 bh0 = *(const half8*)&S[bbase0 + icoB];
        half8 bl0 = *(const half8*)&S[4096 + bbase0 + icoB];
        half8 bh1 = *(const half8*)&S[bbase1 + icoB];
        half8 bl1 = *(const half8*)&S[4096 + bbase1 + icoB];
        acc00 = __builtin_amdgcn_mfma_f32_32x32x16_f16(ah, bh0, acc00, 0, 0, 0);
        acc10 = __builtin_amdgcn_mfma_f32_32x32x16_f16(ah, bl0, acc10, 0, 0, 0);
        acc10 = __builtin_amdgcn_mfma_f32_32x32x16_f16(al, bh0, acc10, 0, 0, 0);
        acc01 = __builtin_amdgcn_mfma_f32_32x32x16_f16(ah, bh1, acc01, 0, 0, 0);
        acc11 = __builtin_amdgcn_mfma_f32_32x32x16_f16(ah, bl1, acc11, 0, 0, 0);
        acc11 = __builtin_amdgcn_mfma_f32_32x32x16_f16(al, bh1, acc11, 0, 0, 0);
      }
    }
  }
  __syncthreads();
  float* sPool = (float*)S;
#pragma unroll
  for (int r = 0; r < 16; ++r) {
    const int mrow = (r & 3) + 8 * (r >> 2) + 4 * g;
    const int mo = w * 32 + mrow;
    sPool[mo * 64 + l31] = acc00[r] + acc10[r] * 9.765625e-4f;
    sPool[mo * 64 + 32 + l31] = acc01[r] + acc11[r] * 9.765625e-4f;
  }
  __syncthreads();
  for (int idx = tid; idx < 3584; idx += 448) {
    const int img = idx / 1792;
    int rem = idx - img * 1792;
    const int och = rem / 28;
    rem -= och * 28;
    const int pr = rem / 14;
    const int pc = rem - pr * 14;
    const int mb = img * 112 + pr * 56 + pc * 2;
    const float a = sPool[mb * 64 + och];
    const float b = sPool[(mb + 1) * 64 + och];
    const float c = sPool[(mb + 28) * 64 + och];
    const float d = sPool[(mb + 29) * 64 + och];
    const float mx = fmaxf(fmaxf(a, b), fmaxf(c, d));
    y2p[((size_t)(img0 + img) * 64 + och) * 196 + (rp * 2 + pr) * 14 + pc] =
        fmaxf(mx + b2[och], 0.f);
  }
}

// ---------------------------------------------------------------------------
// conv3 via MFMA split-f16 implicit GEMM.
// y2p [C,64,14,14] -> feats [C,96,12,12], 3x3, relu.
// 1 img/block, 320 thr = 5 waves; wave w -> m-tile (32 positions), x3 n-tiles.
// K = (ic-chunk 32) x (9 taps as 4 pairs + 1).
// LDS halves: Xhi[0,6272) [196 pix][32 ic ^ ((pix>>1)&3)<<3]
//             Xlo[6272,12544)
//             Bhi[12544,18688) fragment-order [tl][nt][s][g][n32][e8]
//             Blo[18688,24832)
// out staging overlays as float [32][145].
// ---------------------------------------------------------------------------
__global__ __launch_bounds__(320) void conv3_mfma_k(
    const float* __restrict__ y2p, const float* __restrict__ w3,
    const float* __restrict__ b3, float* __restrict__ feats) {
  __shared__ __align__(16) _Float16 S[24832];
  const int img = blockIdx.x;
  const int tid = threadIdx.x;
  const int w = tid >> 6;      // 0..4
  const int lane = tid & 63;
  const int l31 = lane & 31;
  const int g = lane >> 5;
  const int m = w * 32 + l31;  // 0..159 (144+ are dummy)
  const int mc = (m < 144) ? m : 143;
  const int r = mc / 12, c = mc - (mc / 12) * 12;

  f32x16 acch[3] = {};
  f32x16 accl[3] = {};

  const float* inImg = y2p + (size_t)img * 12544;
#pragma unroll 1
  for (int icc = 0; icc < 2; ++icc) {
    __syncthreads();
    // ---- stage X ic-chunk: [196 pix][32 ic], split hi/lo, granule XOR ----
    for (int idx = tid; idx < 6272; idx += 320) {
      const int ic = idx & 31;
      const int p = idx >> 5;  // 0..195
      const float v = inImg[(icc * 32 + ic) * 196 + p];
      const _Float16 h = (_Float16)v;
      const _Float16 l = (_Float16)((v - (float)h) * 1024.0f);
      const int o = p * 32 + (ic ^ (((p >> 1) & 3) << 3));
      S[o] = h;
      S[6272 + o] = l;
    }
#pragma unroll 1
    for (int tc = 0; tc < 5; ++tc) {
      __syncthreads();
      const int ntaps = (tc == 4) ? 1 : 2;
      // ---- stage W in MFMA-fragment order (conflict-free reads) ----
      for (int idx = tid; idx < 3072 * ntaps; idx += 320) {
        const int och = idx % 96;
        const int rest = idx / 96;
        const int tl = (ntaps == 2) ? (rest & 1) : 0;
        const int ic = (ntaps == 2) ? (rest >> 1) : rest;
        const float v = w3[(size_t)och * 576 + (icc * 32 + ic) * 9 + tc * 2 + tl];
        const _Float16 h = (_Float16)v;
        const _Float16 l = (_Float16)((v - (float)h) * 1024.0f);
        const int nt = och >> 5, n = och & 31;
        const int s = ic >> 4, gg = (ic >> 3) & 1, e = ic & 7;
        const int off = ((((tl * 3 + nt) * 2 + s) * 2 + gg) * 32 + n) * 8 + e;
        S[12544 + off] = h;
        S[18688 + off] = l;
      }
      __syncthreads();
#pragma unroll 1
      for (int tl = 0; tl < ntaps; ++tl) {
        const int tap = tc * 2 + tl;
        const int ky = tap / 3, kx = tap - (tap / 3) * 3;
        const int pix = (r + ky) * 14 + (c + kx);
        const int pswz = (pix >> 1) & 3;
        half8 ah[2], al[2];
#pragma unroll
        for (int s = 0; s < 2; ++s) {
          const int o = pix * 32 + ((s * 2 + g) ^ pswz) * 8;
          ah[s] = *(const half8*)&S[o];
          al[s] = *(const half8*)&S[6272 + o];
        }
#pragma unroll
        for (int nt = 0; nt < 3; ++nt) {
#pragma unroll
          for (int s = 0; s < 2; ++s) {
            const int bo = ((((tl * 3 + nt) * 2 + s) * 2 + g) * 32 + l31) * 8;
            half8 bh = *(const half8*)&S[12544 + bo];
            half8 bl = *(const half8*)&S[18688 + bo];
            acch[nt] =
                __builtin_amdgcn_mfma_f32_32x32x16_f16(ah[s], bh, acch[nt], 0, 0, 0);
            accl[nt] =
                __builtin_amdgcn_mfma_f32_32x32x16_f16(ah[s], bl, accl[nt], 0, 0, 0);
            accl[nt] =
                __builtin_amdgcn_mfma_f32_32x32x16_f16(al[s], bh, accl[nt], 0, 0, 0);
          }
        }
      }
    }
  }
  // ---- output: stage per n-tile through LDS (odd stride), coalesced store --
  float* sO = (float*)S;  // [32][145] f32 = 18560 B
  float* outImg = feats + (size_t)img * 13824;
#pragma unroll
  for (int nt = 0; nt < 3; ++nt) {
    __syncthreads();
#pragma unroll
    for (int rr = 0; rr < 16; ++rr) {
      const int row = (rr & 3) + 8 * (rr >> 2) + 4 * g;
      const int pos = w * 32 + row;
      if (pos < 144)
        sO[l31 * 145 + pos] = acch[nt][rr] + accl[nt][rr] * 9.765625e-4f;
    }
    __syncthreads();
    for (int idx = tid; idx < 4608; idx += 320) {
      const int oc = idx / 144;
      const int pos = idx - oc * 144;
      outImg[(nt * 32 + oc) * 144 + pos] =
          fmaxf(sO[oc * 145 + pos] + b3[nt * 32 + oc], 0.f);
    }
  }
}

// ---------------------------------------------------------------------------
// ff GEMM (chunked): featsc [Cl,13824] x w_in[128,13824]^T -> P[8][2048][128]
// ---------------------------------------------------------------------------
__global__ __launch_bounds__(256) void ffgemm_k(
    const float* __restrict__ A, const float* __restrict__ Bw,
    float* __restrict__ P, int frame0, int Cl) {
  __shared__ float sA[32 * 64];
  __shared__ float sB[32 * 128];
  const int mb = blockIdx.x;
  const int kc = blockIdx.y;
  const int tid = threadIdx.x;
  const int tm = tid >> 4, tn = tid & 15;
  const int m0 = tm * 4, n0 = tn * 8;
  float acc[4][8];
#pragma unroll
  for (int m = 0; m < 4; ++m)
#pragma unroll
    for (int n = 0; n < 8; ++n) acc[m][n] = 0.f;
  const int kbase = kc * 1728;
  for (int kt = 0; kt < 1728; kt += 32) {
    __syncthreads();
#pragma unroll
    for (int i = 0; i < 2; ++i) {
      int idx = tid + i * 256;
      int row = idx >> 3, kq = idx & 7;
      int rowc = mb * 64 + row;
      if (rowc >= Cl) rowc = Cl - 1;
      float4 v = *(const float4*)(A + (size_t)rowc * 13824 + kbase + kt + kq * 4);
      sA[(kq * 4 + 0) * 64 + row] = v.x;
      sA[(kq * 4 + 1) * 64 + row] = v.y;
      sA[(kq * 4 + 2) * 64 + row] = v.z;
      sA[(kq * 4 + 3) * 64 + row] = v.w;
    }
#pragma unroll
    for (int i = 0; i < 4; ++i) {
      int idx = tid + i * 256;
      int n = idx >> 3, kq = idx & 7;
      float4 v = *(const float4*)(Bw + (size_t)n * 13824 + kbase + kt + kq * 4);
      sB[(kq * 4 + 0) * 128 + n] = v.x;
      sB[(kq * 4 + 1) * 128 + n] = v.y;
      sB[(kq * 4 + 2) * 128 + n] = v.z;
      sB[(kq * 4 + 3) * 128 + n] = v.w;
    }
    __syncthreads();
#pragma unroll
    for (int k = 0; k < 32; ++k) {
      float a4[4], b8[8];
      *(float4*)a4 = *(const float4*)&sA[k * 64 + m0];
      *(float4*)(b8) = *(const float4*)&sB[k * 128 + n0];
      *(float4*)(b8 + 4) = *(const float4*)&sB[k * 128 + n0 + 4];
#pragma unroll
      for (int m = 0; m < 4; ++m)
#pragma unroll
        for (int n = 0; n < 8; ++n) acc[m][n] += a4[m] * b8[n];
    }
  }
  float* Pp = P + ((size_t)kc * 2048 + (size_t)frame0 + (size_t)mb * 64) * 128;
#pragma unroll
  for (int m = 0; m < 4; ++m) {
    if (mb * 64 + m0 + m < Cl) {
      *(float4*)&Pp[(m0 + m) * 128 + n0] = *(float4*)&acc[m][0];
      *(float4*)&Pp[(m0 + m) * 128 + n0 + 4] = *(float4*)&acc[m][4];
    }
  }
}

__global__ __launch_bounds__(256) void ffreduce_k(const float* __restrict__ P,
                                                  float* __restrict__ ffo) {
  const int i = blockIdx.x * 256 + threadIdx.x;
  float s = 0.f;
#pragma unroll
  for (int kcc = 0; kcc < 8; ++kcc) s += P[(size_t)kcc * 262144 + i];
  ffo[i] = s;
}

// ---------------------------------------------------------------------------
// Recurrent LIF scan (unchanged)
// ---------------------------------------------------------------------------
__global__ __launch_bounds__(64) void scan_k(
    const float* __restrict__ ff, const float* __restrict__ w_rec,
    const float* __restrict__ w_fc, const float* __restrict__ b_fc,
    float* __restrict__ out) {
#pragma clang fp contract(off)
  __shared__ float sWr[16384];
  const int b = blockIdx.x;
  const int t = threadIdx.x;
  for (int idx = t; idx < 16384; idx += 64) {
    int hh = idx >> 7, j = idx & 127;
    sWr[j * 128 + hh] = w_rec[idx];
  }
  float wf0[10], wf1[10], bf[10];
#pragma unroll
  for (int c = 0; c < 10; ++c) {
    wf0[c] = w_fc[c * 128 + t];
    wf1[c] = w_fc[c * 128 + 64 + t];
    bf[c] = b_fc[c];
  }
  __syncthreads();
  float v0 = 0.f, v1 = 0.f, i0 = 0.f, i1 = 0.f;
  float vr[10], ir[10], vmax[10];
#pragma unroll
  for (int c = 0; c < 10; ++c) {
    vr[c] = 0.f;
    ir[c] = 0.f;
    vmax[c] = -1e30f;
  }
  unsigned long long pm0 = 0ull, pm1 = 0ull;
  const float* ffb = ff + (size_t)b * 8192;
#pragma unroll 1
  for (int ts = 0; ts < 64; ++ts) {
    const float vd0 = v0 + 0.1f * (i0 - v0);
    const float vd1 = v1 + 0.1f * (i1 - v1);
    const float id0 = i0 - 0.2f * i0;
    const float id1 = i1 - 0.2f * i1;
    const bool z0 = (vd0 - 0.4f) > 0.f;
    const bool z1 = (vd1 - 0.4f) > 0.f;
    v0 = z0 ? 0.f : vd0;
    v1 = z1 ? 0.f : vd1;
    float rec0 = 0.f, rec1 = 0.f;
    unsigned long long mm = pm0;
    while (mm) {
      int j = __ffsll(mm) - 1;
      mm &= mm - 1;
      rec0 += sWr[j * 128 + t];
      rec1 += sWr[j * 128 + t + 64];
    }
    mm = pm1;
    while (mm) {
      int j = __ffsll(mm) - 1;
      mm &= mm - 1;
      rec0 += sWr[(j + 64) * 128 + t];
      rec1 += sWr[(j + 64) * 128 + t + 64];
    }
    i0 = (id0 + ffb[ts * 128 + t]) + rec0;
    i1 = (id1 + ffb[ts * 128 + 64 + t]) + rec1;
    pm0 = __ballot(z0);
    pm1 = __ballot(z1);
#pragma unroll
    for (int c = 0; c < 10; ++c) {
      float val = (z0 ? wf0[c] : 0.f) + (z1 ? wf1[c] : 0.f);
      val += __shfl_xor(val, 1);
      val += __shfl_xor(val, 2);
      val += __shfl_xor(val, 4);
      val += __shfl_xor(val, 8);
      val += __shfl_xor(val, 16);
      val += __shfl_xor(val, 32);
      const float ro = val + bf[c];
      vr[c] = vr[c] + 0.1f * (ir[c] - vr[c]);
      vmax[c] = fmaxf(vmax[c], vr[c]);
      ir[c] = (ir[c] - 0.2f * ir[c]) + ro;
    }
  }
  if (t == 0) {
    float M = vmax[0];
#pragma unroll
    for (int c = 1; c < 10; ++c) M = fmaxf(M, vmax[c]);
    float s = 0.f;
#pragma unroll
    for (int c = 0; c < 10; ++c) s += expf(vmax[c] - M);
    const float ls = logf(s);
#pragma unroll
    for (int c = 0; c < 10; ++c) out[b * 10 + c] = vmax[c] - M - ls;
  }
}

// ---------------------------------------------------------------------------
extern "C" void kernel_launch(void* const* d_in, const int* in_sizes, int n_in,
                              void* d_out, int out_size, void* d_ws,
                              size_t ws_size, hipStream_t stream) {
  (void)in_sizes;
  (void)n_in;
  (void)out_size;
  const float* x = (const float*)d_in[0];
  const float* w1 = (const float*)d_in[1];
  const float* b1 = (const float*)d_in[2];
  const float* w2 = (const float*)d_in[3];
  const float* b2 = (const float*)d_in[4];
  const float* w3 = (const float*)d_in[5];
  const float* b3 = (const float*)d_in[6];
  const float* w_in = (const float*)d_in[7];
  const float* w_rec = (const float*)d_in[8];
  const float* w_fc = (const float*)d_in[9];
  const float* b_fc = (const float*)d_in[10];
  float* out = (float*)d_out;
  char* ws = (char*)d_ws;

  const size_t HDR = 1048576ull + 8388608ull;
  const size_t PERF = 115200ull + 50176ull + 55296ull;
  int C = 32;
  for (int c = 2048; c >= 32; c >>= 1) {
    if (HDR + (size_t)c * PERF <= ws_size) { C = c; break; }
  }
  float* ffbuf = (float*)ws;
  float* P = (float*)(ws + 1048576ull);
  float* y1c = (float*)(ws + HDR);
  float* y2c = y1c + (size_t)C * 28800;
  float* fc = y2c + (size_t)C * 12544;

  const int nChunks = 2048 / C;
  const int mbN = (C + 63) / 64;
  for (int ch = 0; ch < nChunks; ++ch) {
    const int f0 = ch * C;
    conv1_k<<<C, 256, 0, stream>>>(x + (size_t)f0 * 4096, w1, b1, y1c);
    conv2_mfma_k<<<dim3(7, C / 2), 448, 0, stream>>>(y1c, w2, b2, y2c);
    conv3_mfma_k<<<C, 320, 0, stream>>>(y2c, w3, b3, fc);
    ffgemm_k<<<dim3(mbN, 8), 256, 0, stream>>>(fc, w_in, P, f0, C);
  }
  ffreduce_k<<<1024, 256, 0, stream>>>(P, ffbuf);
  scan_k<<<32, 64, 0, stream>>>(ffbuf, w_rec, w_fc, b_fc, out);
}